// Round 11
// baseline (140.891 us; speedup 1.0000x reference)
//
#include <hip/hip_runtime.h>

typedef __attribute__((ext_vector_type(8))) short short8;
typedef __attribute__((ext_vector_type(4))) float f32x4;

#define SGC (-1.44269504088896341f)   /* -log2(e): sigmoid prescale */
#define THC ( 2.88539008177792681f)   /* 2*log2(e): tanh prescale   */

__device__ __forceinline__ unsigned short f2bf(float f){
  unsigned u = __float_as_uint(f);
  return (unsigned short)((u + 0x7fffu + ((u >> 16) & 1u)) >> 16);
}
__device__ __forceinline__ float bf2f(unsigned short b){
  return __uint_as_float(((unsigned)b) << 16);
}
__device__ __forceinline__ unsigned f2bf_cvt(float f){
  unsigned r;
  asm("v_cvt_pk_bf16_f32 %0, %1, %1" : "=v"(r) : "v"(f));
  return r;
}
__device__ __forceinline__ unsigned f2bf_pk(float lo, float hi){
  unsigned r;
  asm("v_cvt_pk_bf16_f32 %0, %1, %2" : "=v"(r) : "v"(lo), "v"(hi));
  return r;
}

// ---------------- weight conversion: fp32 -> bf16 in ws ----------------
// wgt layout (u16 elems):
//   whhT_b [384*128]  @0        (PRESCALED: rows<256 *SGC, rows>=256 *THC)
//   W1b    [128*96]   @49152    (96 = 68 padded, zeros)
//   W2b    [128*128]  @61440
//   Wf1b   [256*1152] @77824
//   Wf2b   [128*256]  @372736
//   Wf3b   [64*128]   @405504
//   whhN_b [192*64]   @413696   (PRESCALED: rows<128 *SGC, rows>=128 *THC)
__global__ __launch_bounds__(256) void k_prep(
    const float* __restrict__ Whh_t, const float* __restrict__ W1,
    const float* __restrict__ W2,    const float* __restrict__ Wf1,
    const float* __restrict__ Wf2,   const float* __restrict__ Wf3,
    const float* __restrict__ Whh_n,
    unsigned short* __restrict__ wgt)
{
  int i = blockIdx.x * 256 + threadIdx.x;
  if (i < 49152){
    int g = i >> 7;
    float s = (g < 256) ? SGC : THC;
    wgt[i] = f2bf(Whh_t[i] * s); return;
  }
  i -= 49152;
  if (i < 12288){ int r = i / 96, c = i % 96;
    wgt[49152 + i] = (c < 68) ? f2bf(W1[r*68 + c]) : (unsigned short)0; return; }
  i -= 12288;
  if (i < 16384){ wgt[61440 + i] = f2bf(W2[i]); return; }
  i -= 16384;
  if (i < 294912){ wgt[77824 + i] = f2bf(Wf1[i]); return; }
  i -= 294912;
  if (i < 32768){ wgt[372736 + i] = f2bf(Wf2[i]); return; }
  i -= 32768;
  if (i < 8192){ wgt[405504 + i] = f2bf(Wf3[i]); return; }
  i -= 8192;
  if (i < 12288){
    int g = i >> 6;
    float s = (g < 128) ? SGC : THC;
    wgt[413696 + i] = f2bf(Whh_n[i] * s); return;
  }
}

// ---------------- neighbor GRU + pooling + MLP1/2 (fused, 4-batch) ----------------
// 512 blocks x 1024 threads; block = 4 batches (bi = tid>>8) sharing one
// whh2 copy. LDS 72704 B -> EXACTLY 2 blocks/CU = 32 waves/CU (HW max),
// and 512 blocks / 256 CU = ONE clean residency round (no quantization).
// Layout: whh2 24576 | wx 3072 | 4 x pb{hall 9216, xpk/pool 2048}.
// Post-GRU reuse: sfl(bi) = whh2 + bi*1536 u16; h1l(bi) = hall(bi) base.
// launch_bounds (1024,8): VGPR cap 64 — same per-thread body compiled to
// 52 VGPR in r8/r10, so no spill expected (watch hbm_bytes if it does).
__global__ __launch_bounds__(1024, 8) void k_gru_n(
    const float* __restrict__ ttraj, const float* __restrict__ ntraj,
    const float* __restrict__ rang,  const float* __restrict__ nmask,
    const float* __restrict__ Wih_n,
    const float* __restrict__ bih_n, const float* __restrict__ bhh_n,
    const unsigned short* __restrict__ wgt,
    const float* __restrict__ b1, const float* __restrict__ b2,
    unsigned short* __restrict__ combined)      // [2048][1152] bf16
{
  __shared__ char smem[72704];
  const int tid = threadIdx.x;
  const int bi = tid >> 8, lt = tid & 255;
  const int w = lt >> 6, u = (lt >> 4) & 3, c = lt & 15;
  const int b = blockIdx.x * 4 + bi;
  const unsigned short* whhN_b = wgt + 413696;   // [192][64] prescaled

  unsigned short* whh2 = (unsigned short*)smem;                 // [12][2][64][8]
  unsigned short* wx   = whh2 + 12288;                          // [12][16][8]
  char* pb = smem + 27648 + bi * 11264;
  unsigned short* hall = (unsigned short*)pb;                   // 4 x [16][72]
  unsigned short* hb   = hall + w * 1152;
  unsigned* xpk = (unsigned*)(pb + 9216);                       // [8][64] u32
  float* pool   = (float*)(pb + 9216);                          // alias (512 f32)
  unsigned short* sfl = whh2 + bi * 1536;                       // [16][96]  reuse
  unsigned short* h1l = hall;                                   // [16][136] reuse

  // stage hh weights lane-linear (shared): whh2[nt][half][u*16+c][8]
  for (int i = tid; i < 1536; i += 1024){
    int nt = i >> 7, rem = i & 127;
    int hf = rem >> 6, uu = (rem >> 4) & 3, cc = rem & 15;
    *(short8*)&whh2[nt*1024 + hf*512 + (uu*16+cc)*8] =
        *(const short8*)&whhN_b[(nt*16+cc)*64 + hf*32 + uu*8];
  }
  // stage x-tiles (shared): rows 64,65,66 = W0*s, W1*s, bias*s (rest 0)
  if (tid < 192){
    int t = tid >> 4, cc = tid & 15;
    float s = (t < 8) ? SGC : THC;
    int g = (t < 4) ? (t*16 + cc) : (t < 8) ? (64 + (t-4)*16 + cc) : (128 + (t-8)*16 + cc);
    float bsum = (t < 8) ? (bih_n[g] + bhh_n[g]) : bih_n[g];
    unsigned short* p = &wx[t*128 + cc*8];
    *(short8*)p = (short8){0,0,0,0,0,0,0,0};
    p[0] = f2bf(Wih_n[g*2]   * s);
    p[1] = f2bf(Wih_n[g*2+1] * s);
    p[2] = f2bf(bsum * s);
  }
  // stage trajectories packed bf16: xpk[step][seq] (per batch)
  {
    float4 v = ((const float4*)(ntraj + (size_t)b * 1024))[lt];
    int n = lt >> 2, p = (lt & 3) * 2;
    xpk[p*64 + n]       = f2bf_pk(v.x, v.y);
    xpk[(p+1)*64 + n]   = f2bf_pk(v.z, v.w);
  }
  __syncthreads();

  float bh_[4];
#pragma unroll
  for (int gt = 0; gt < 4; ++gt) bh_[gt] = bhh_n[128 + gt*16 + c] * THC;

  float hcur[4][4];
#pragma unroll
  for (int gt=0; gt<4; ++gt)
#pragma unroll
    for (int q=0; q<4; ++q) hcur[gt][q] = 0.0f;

  auto gates = [&](int gt, const f32x4& aR, const f32x4& aZ, const f32x4& aN, const f32x4& aX){
#pragma unroll
    for (int q = 0; q < 4; ++q){
      float r = __builtin_amdgcn_rcpf(1.0f + __builtin_amdgcn_exp2f(aR[q]));
      float z = __builtin_amdgcn_rcpf(1.0f + __builtin_amdgcn_exp2f(aZ[q]));
      float hn = aN[q] + bh_[gt];
      float pn = __builtin_fmaf(r, hn, aX[q]);
      float E = __builtin_amdgcn_exp2f(pn);
      float n = __builtin_fmaf(-2.0f, __builtin_amdgcn_rcpf(E + 1.0f), 1.0f);
      float hnew = __builtin_fmaf(z, hcur[gt][q] - n, n);
      hcur[gt][q] = hnew;
      hb[(u*4+q)*72 + gt*16 + c] = (unsigned short)f2bf_cvt(hnew);
    }
  };

  const int lane8 = (u*16 + c) * 8;
  const f32x4 zz = {0.f,0.f,0.f,0.f};

#pragma unroll 1
  for (int st = 0; st < 8; ++st){
    // augmented A chunk a2 = [x0, x1, 1.0, 0...] (u==0 lanes only)
    unsigned p01 = xpk[st*64 + w*16 + c];
    bool u0 = (u == 0);
    union { unsigned ui[4]; short8 s8; } a2u;
    a2u.ui[0] = u0 ? p01 : 0u;
    a2u.ui[1] = u0 ? 0x3F80u : 0u;   // bf16(1.0) in halfword 2
    a2u.ui[2] = 0u; a2u.ui[3] = 0u;
    short8 a2 = a2u.s8;

    if (st > 0){
      short8 a0 = *(short8*)&hb[c*72 + u*8];
      short8 a1 = *(short8*)&hb[c*72 + 32 + u*8];
#pragma unroll
      for (int gt = 0; gt < 4; ++gt){
        const unsigned short* pr = whh2 + gt*1024 + lane8;
        const unsigned short* pz = whh2 + (4+gt)*1024 + lane8;
        const unsigned short* pq = whh2 + (8+gt)*1024 + lane8;
        short8 bxr = *(const short8*)&wx[gt*128 + c*8];
        short8 bxz = *(const short8*)&wx[(4+gt)*128 + c*8];
        short8 bxn = *(const short8*)&wx[(8+gt)*128 + c*8];
        f32x4 aR = __builtin_amdgcn_mfma_f32_16x16x32_bf16(a0, *(const short8*)pr, zz, 0,0,0);
        aR = __builtin_amdgcn_mfma_f32_16x16x32_bf16(a1, *(const short8*)(pr+512), aR, 0,0,0);
        aR = __builtin_amdgcn_mfma_f32_16x16x32_bf16(a2, bxr, aR, 0,0,0);
        f32x4 aZ = __builtin_amdgcn_mfma_f32_16x16x32_bf16(a0, *(const short8*)pz, zz, 0,0,0);
        aZ = __builtin_amdgcn_mfma_f32_16x16x32_bf16(a1, *(const short8*)(pz+512), aZ, 0,0,0);
        aZ = __builtin_amdgcn_mfma_f32_16x16x32_bf16(a2, bxz, aZ, 0,0,0);
        f32x4 aN = __builtin_amdgcn_mfma_f32_16x16x32_bf16(a0, *(const short8*)pq, zz, 0,0,0);
        aN = __builtin_amdgcn_mfma_f32_16x16x32_bf16(a1, *(const short8*)(pq+512), aN, 0,0,0);
        f32x4 aX = __builtin_amdgcn_mfma_f32_16x16x32_bf16(a2, bxn, zz, 0,0,0);
        gates(gt, aR, aZ, aN, aX);
      }
    } else {
#pragma unroll
      for (int gt = 0; gt < 4; ++gt){
        short8 bxr = *(const short8*)&wx[gt*128 + c*8];
        short8 bxz = *(const short8*)&wx[(4+gt)*128 + c*8];
        short8 bxn = *(const short8*)&wx[(8+gt)*128 + c*8];
        f32x4 aR = __builtin_amdgcn_mfma_f32_16x16x32_bf16(a2, bxr, zz, 0,0,0);
        f32x4 aZ = __builtin_amdgcn_mfma_f32_16x16x32_bf16(a2, bxz, zz, 0,0,0);
        f32x4 aX = __builtin_amdgcn_mfma_f32_16x16x32_bf16(a2, bxn, zz, 0,0,0);
        gates(gt, aR, aZ, zz, aX);
      }
    }
  }
  __syncthreads();   // GRU done for all 4 batches; whh2 now dead -> sfl reuse

  // ---- sector pooling (pool aliases xpk; positions from L2-hot ntraj) ----
  for (int i = lt; i < 1536; i += 256) sfl[i] = 0;
  if (lt < 64){
    int n = lt;
    const float* nb = ntraj + (size_t)b*1024 + n*16;
    float px = nb[14], py = nb[15];
    float vx = px - nb[12], vy = py - nb[13];
    float m   = nmask[(size_t)b*64 + n];
    float ang = rang[(size_t)b*64 + n];
    float tx = ttraj[(size_t)b*16 + 14], ty = ttraj[(size_t)b*16 + 15];
    float dx = px - tx, dy = py - ty;
    float dist = __builtin_amdgcn_sqrtf(dx*dx + dy*dy);
    int sid = (int)(ang / 0.78539816339744830962f);
    sid = sid < 0 ? 0 : (sid > 7 ? 7 : sid);
    bool valid = m > 0.0f;
    float wv = valid ? __builtin_amdgcn_exp2f(dist * -0.14426950408889634f) : 0.0f;
    pool[n]       = valid ? dist : 0.0f;
    pool[64 + n]  = valid ? vx   : 0.0f;
    pool[128 + n] = valid ? vy   : 0.0f;
    pool[192 + n] = wv;
    pool[256 + n] = valid ? (float)sid : -1.0f;
  }
  __syncthreads();
  if (lt < 8){
    int s = lt;
    float cnt=0.f, sd=0.f, sx=0.f, sy=0.f, sw=0.f;
#pragma unroll 4
    for (int n=0; n<64; ++n){
      if (pool[256+n] == (float)s){
        cnt += 1.f; sd += pool[n]; sx += pool[64+n]; sy += pool[128+n]; sw += pool[192+n];
      }
    }
    float inv = (cnt > 0.f) ? __builtin_amdgcn_rcpf(cnt) : 0.f;
    pool[320 + s] = cnt;
    pool[328 + s] = sd * inv;
    pool[336 + s] = sx * inv;
    pool[344 + s] = sy * inv;
    pool[352 + s] = __builtin_amdgcn_rcpf(sw + 1e-8f);
  }
  __syncthreads();
#pragma unroll
  for (int rep = 0; rep < 2; ++rep){
    int p = lt + rep*256;
    int s = p >> 6, h = p & 63;
    float fs = (float)s;
    float a = 0.f;
#pragma unroll 4
    for (int n = 0; n < 64; ++n){
      float wmv = (pool[256+n] == fs) ? pool[192+n] : 0.f;
      float nf  = bf2f(hall[(n>>4)*1152 + (n&15)*72 + h]);
      a += wmv * nf;
    }
    sfl[s*96 + 4 + h] = (unsigned short)f2bf_cvt(a * pool[352+s]);
  }
  if (lt < 32){
    int s = lt >> 2, cc = lt & 3;
    sfl[s*96 + cc] = (unsigned short)f2bf_cvt(pool[320 + cc*8 + s]);
  }
  __syncthreads();   // sfl ready; hall now dead -> h1l reuse

  // ---- fused MLP1 (96->128) : wave w handles nt = 2w, 2w+1 ----
  const unsigned short* w1b = wgt + 49152;   // [128][96]
  const unsigned short* w2b = wgt + 61440;   // [128][128]
  f32x4 accA[2];
#pragma unroll
  for (int i=0;i<2;++i) accA[i] = zz;
#pragma unroll
  for (int kc=0; kc<3; ++kc){
    short8 a = (short8){0,0,0,0,0,0,0,0};
    if (c < 8) a = *(const short8*)&sfl[c*96 + kc*32 + u*8];
#pragma unroll
    for (int i=0;i<2;++i){
      int nt = w*2 + i;
      short8 bb = *(const short8*)&w1b[(nt*16+c)*96 + kc*32 + u*8];
      accA[i] = __builtin_amdgcn_mfma_f32_16x16x32_bf16(a, bb, accA[i], 0,0,0);
    }
  }
#pragma unroll
  for (int i=0;i<2;++i){
    int nt = w*2 + i;
    float bias = b1[nt*16 + c];
#pragma unroll
    for (int q=0;q<4;++q){
      float v = accA[i][q] + bias; v = v > 0.f ? v : 0.f;
      h1l[(u*4+q)*136 + nt*16 + c] = (unsigned short)f2bf_cvt(v);
    }
  }
  __syncthreads();

  // ---- fused MLP2 (128->128) -> combined[b][128 + s*128 + col] ----
  f32x4 accB[2];
#pragma unroll
  for (int i=0;i<2;++i) accB[i] = zz;
#pragma unroll
  for (int kc=0; kc<4; ++kc){
    short8 a = *(short8*)&h1l[c*136 + kc*32 + u*8];
#pragma unroll
    for (int i=0;i<2;++i){
      int nt = w*2 + i;
      short8 bb = *(const short8*)&w2b[(nt*16+c)*128 + kc*32 + u*8];
      accB[i] = __builtin_amdgcn_mfma_f32_16x16x32_bf16(a, bb, accB[i], 0,0,0);
    }
  }
#pragma unroll
  for (int i=0;i<2;++i){
    int nt = w*2 + i;
    float bias = b2[nt*16 + c];
#pragma unroll
    for (int q=0;q<4;++q){
      int row = u*4 + q;              // sector index; rows 8..15 are pad
      if (row < 8){
        float v = accB[i][q] + bias; v = v > 0.f ? v : 0.f;
        combined[(size_t)b*1152 + 128 + row*128 + nt*16 + c] = (unsigned short)f2bf_cvt(v);
      }
    }
  }
}

// ---------------- target GRU: 128 blocks x 256 thr (4 waves) ----------------
__global__ __launch_bounds__(256) void k_gru_t(
    const float* __restrict__ ttraj,
    const float* __restrict__ Wih_t, const float* __restrict__ bih_t, const float* __restrict__ bhh_t,
    const unsigned short* __restrict__ wgt,      // whhT_b [384][128] @0
    unsigned short* __restrict__ combined)       // [2048][1152] bf16
{
  __shared__ char smem[9728];
  const int tid = threadIdx.x, w = tid >> 6, u = (tid >> 4) & 3, c = tid & 15;
  unsigned short* hb0 = (unsigned short*)smem;             // [16][136]
  unsigned short* hb1 = (unsigned short*)(smem + 4352);    // [16][136]
  float* xs = (float*)(smem + 8704);                       // [16][16]

  xs[tid] = ttraj[(size_t)blockIdx.x*256 + tid];

  int ntg[6];
  ntg[0] = 2*w; ntg[1] = 2*w+1;
  ntg[2] = 8+2*w; ntg[3] = 9+2*w;
  ntg[4] = 16+2*w; ntg[5] = 17+2*w;

  short8 Bf[6][4];
#pragma unroll
  for (int lt2 = 0; lt2 < 6; ++lt2){
    const unsigned short* wp = wgt + (ntg[lt2]*16 + c)*128 + u*8;
#pragma unroll
    for (int kk = 0; kk < 4; ++kk)
      Bf[lt2][kk] = *(const short8*)(wp + kk*32);
  }

  float Wr0[2],Wr1[2],BR[2],Wz0[2],Wz1[2],BZ[2],Wn0[2],Wn1[2],BI[2],BH[2];
#pragma unroll
  for (int gt = 0; gt < 2; ++gt){
    int g = w*32 + gt*16 + c;
    Wr0[gt]=Wih_t[g*2]*SGC;        Wr1[gt]=Wih_t[g*2+1]*SGC;        BR[gt]=(bih_t[g]+bhh_t[g])*SGC;
    Wz0[gt]=Wih_t[(128+g)*2]*SGC;  Wz1[gt]=Wih_t[(128+g)*2+1]*SGC;  BZ[gt]=(bih_t[128+g]+bhh_t[128+g])*SGC;
    Wn0[gt]=Wih_t[(256+g)*2]*THC;  Wn1[gt]=Wih_t[(256+g)*2+1]*THC;  BI[gt]=bih_t[256+g]*THC; BH[gt]=bhh_t[256+g]*THC;
  }
  float hcur[2][4];
#pragma unroll
  for (int gt=0; gt<2; ++gt)
#pragma unroll
    for (int q=0; q<4; ++q) hcur[gt][q] = 0.0f;
  __syncthreads();

#pragma unroll 1
  for (int st = 0; st < 8; ++st){
    unsigned short* rbuf = (st & 1) ? hb0 : hb1;
    unsigned short* wbuf = (st & 1) ? hb1 : hb0;
    f32x4 acc[6];
    if (st > 0){
      short8 a0 = *(short8*)&rbuf[c*136 + u*8];
      short8 a1 = *(short8*)&rbuf[c*136 + 32 + u*8];
      short8 a2 = *(short8*)&rbuf[c*136 + 64 + u*8];
      short8 a3 = *(short8*)&rbuf[c*136 + 96 + u*8];
#pragma unroll
      for (int lt2 = 0; lt2 < 6; ++lt2){
        f32x4 t = {0.f,0.f,0.f,0.f};
        t = __builtin_amdgcn_mfma_f32_16x16x32_bf16(a0, Bf[lt2][0], t, 0,0,0);
        t = __builtin_amdgcn_mfma_f32_16x16x32_bf16(a1, Bf[lt2][1], t, 0,0,0);
        t = __builtin_amdgcn_mfma_f32_16x16x32_bf16(a2, Bf[lt2][2], t, 0,0,0);
        acc[lt2] = __builtin_amdgcn_mfma_f32_16x16x32_bf16(a3, Bf[lt2][3], t, 0,0,0);
      }
    } else {
#pragma unroll
      for (int lt2 = 0; lt2 < 6; ++lt2) acc[lt2] = (f32x4){0.f,0.f,0.f,0.f};
    }
#pragma unroll
    for (int gt = 0; gt < 2; ++gt){
#pragma unroll
      for (int q = 0; q < 4; ++q){
        int sq = u*4 + q;
        float x0 = xs[sq*16 + st*2], x1 = xs[sq*16 + st*2 + 1];
        float rp = __builtin_fmaf(Wr0[gt], x0, __builtin_fmaf(Wr1[gt], x1, acc[gt][q] + BR[gt]));
        float zp = __builtin_fmaf(Wz0[gt], x0, __builtin_fmaf(Wz1[gt], x1, acc[2+gt][q] + BZ[gt]));
        float r = __builtin_amdgcn_rcpf(1.0f + __builtin_amdgcn_exp2f(rp));
        float z = __builtin_amdgcn_rcpf(1.0f + __builtin_amdgcn_exp2f(zp));
        float hnv = acc[4+gt][q] + BH[gt];
        float pn = __builtin_fmaf(Wn0[gt], x0, __builtin_fmaf(Wn1[gt], x1, __builtin_fmaf(r, hnv, BI[gt])));
        float E = __builtin_amdgcn_exp2f(pn);
        float n = __builtin_fmaf(-2.0f, __builtin_amdgcn_rcpf(E + 1.0f), 1.0f);
        float hnew = __builtin_fmaf(z, hcur[gt][q] - n, n);
        hcur[gt][q] = hnew;
        if (st < 7){
          wbuf[sq*136 + w*32 + gt*16 + c] = (unsigned short)f2bf_cvt(hnew);
        } else {
          int row = blockIdx.x*16 + sq;
          combined[(size_t)row*1152 + w*32 + gt*16 + c] = (unsigned short)f2bf_cvt(hnew);
        }
      }
    }
    if (st < 7) __syncthreads();
  }
}

// ---------------- head: 128 blocks x 256 thr (4 waves) ----------------
__global__ __launch_bounds__(256) void k_head(
    const unsigned short* __restrict__ combined,
    const unsigned short* __restrict__ wgt,
    const float* __restrict__ bf1, const float* __restrict__ bf2, const float* __restrict__ bf3,
    const float* __restrict__ lng, const float* __restrict__ lnb,
    float* __restrict__ out)
{
  __shared__ char smem[15104];
  const int tid = threadIdx.x, w = tid >> 6, u = (tid >> 4) & 3, c = tid & 15;
  unsigned short* f1b = (unsigned short*)smem;                 // [16][264]
  unsigned short* f2b = (unsigned short*)(smem + 8448);        // [16][136]
  float* bf1s = (float*)(smem + 12800); float* bf2s = (float*)(smem + 13824);
  float* bf3s = (float*)(smem + 14336);
  float* lngs = (float*)(smem + 14592); float* lnbs = (float*)(smem + 14848);
  const unsigned short* wf1b = wgt + 77824;
  const unsigned short* wf2b = wgt + 372736;
  const unsigned short* wf3b = wgt + 405504;
  bf1s[tid] = bf1[tid];
  if (tid < 128) bf2s[tid] = bf2[tid];
  if (tid < 64){ bf3s[tid] = bf3[tid]; lngs[tid] = lng[tid]; lnbs[tid] = lnb[tid]; }
  __syncthreads();
  const int rowb = blockIdx.x * 16;

  f32x4 acc[4];
#pragma unroll
  for (int i=0; i<4; ++i) acc[i] = (f32x4){0.f,0.f,0.f,0.f};
#pragma unroll 4
  for (int kc=0; kc<36; ++kc){
    short8 a = *(const short8*)&combined[(size_t)(rowb + c)*1152 + kc*32 + u*8];
#pragma unroll
    for (int i=0; i<4; ++i){
      int nt = w*4 + i;
      short8 bb = *(const short8*)&wf1b[(size_t)(nt*16+c)*1152 + kc*32 + u*8];
      acc[i] = __builtin_amdgcn_mfma_f32_16x16x32_bf16(a, bb, acc[i], 0,0,0);
    }
  }
#pragma unroll
  for (int i=0; i<4; ++i){
    int nt = w*4 + i;
    float bias = bf1s[nt*16+c];
#pragma unroll
    for (int q=0; q<4; ++q){
      float v = acc[i][q] + bias; v = v > 0.f ? v : 0.f;
      f1b[(u*4+q)*264 + nt*16 + c] = (unsigned short)f2bf_cvt(v);
    }
  }
  __syncthreads();

  f32x4 acc2[2];
#pragma unroll
  for (int i=0; i<2; ++i) acc2[i] = (f32x4){0.f,0.f,0.f,0.f};
#pragma unroll
  for (int kc=0; kc<8; ++kc){
    short8 a = *(short8*)&f1b[c*264 + kc*32 + u*8];
#pragma unroll
    for (int i=0; i<2; ++i){
      int nt = w*2 + i;
      short8 bb = *(const short8*)&wf2b[(nt*16+c)*256 + kc*32 + u*8];
      acc2[i] = __builtin_amdgcn_mfma_f32_16x16x32_bf16(a, bb, acc2[i], 0,0,0);
    }
  }
#pragma unroll
  for (int i=0; i<2; ++i){
    int nt = w*2 + i;
    float bias = bf2s[nt*16+c];
#pragma unroll
    for (int q=0; q<4; ++q){
      float v = acc2[i][q] + bias; v = v > 0.f ? v : 0.f;
      f2b[(u*4+q)*136 + nt*16 + c] = (unsigned short)f2bf_cvt(v);
    }
  }
  __syncthreads();

  f32x4 acc3[4];
#pragma unroll
  for (int nt=0; nt<4; ++nt) acc3[nt] = (f32x4){0.f,0.f,0.f,0.f};
#pragma unroll
  for (int kc=0; kc<4; ++kc){
    short8 a = *(short8*)&f2b[c*136 + kc*32 + u*8];
#pragma unroll
    for (int nt=0; nt<4; ++nt){
      short8 bb = *(const short8*)&wf3b[(nt*16+c)*128 + kc*32 + u*8];
      acc3[nt] = __builtin_amdgcn_mfma_f32_16x16x32_bf16(a, bb, acc3[nt], 0,0,0);
    }
  }
  if (w == 0){
    float v[4][4];
#pragma unroll
    for (int nt=0; nt<4; ++nt){
      float bias = bf3s[nt*16+c];
#pragma unroll
      for (int q=0; q<4; ++q){
        float t = acc3[nt][q] + bias; v[nt][q] = t > 0.f ? t : 0.f;
      }
    }
#pragma unroll
    for (int q=0; q<4; ++q){
      float p = v[0][q] + v[1][q] + v[2][q] + v[3][q];
      p += __shfl_xor(p, 1); p += __shfl_xor(p, 2); p += __shfl_xor(p, 4); p += __shfl_xor(p, 8);
      float mu = p * 0.015625f;
      float d0 = v[0][q]-mu, d1 = v[1][q]-mu, d2 = v[2][q]-mu, d3 = v[3][q]-mu;
      float p2 = d0*d0 + d1*d1 + d2*d2 + d3*d3;
      p2 += __shfl_xor(p2, 1); p2 += __shfl_xor(p2, 2); p2 += __shfl_xor(p2, 4); p2 += __shfl_xor(p2, 8);
      float rstd = __builtin_amdgcn_rsqf(p2 * 0.015625f + 1e-5f);
      int row = rowb + u*4 + q;
#pragma unroll
      for (int nt=0; nt<4; ++nt){
        int col = nt*16 + c;
        out[(size_t)row*64 + col] = (v[nt][q] - mu) * rstd * lngs[col] + lnbs[col];
      }
    }
  }
}

extern "C" void kernel_launch(void* const* d_in, const int* in_sizes, int n_in,
                              void* d_out, int out_size, void* d_ws, size_t ws_size,
                              hipStream_t stream)
{
  const float* ttraj = (const float*)d_in[0];
  const float* ntraj = (const float*)d_in[1];
  const float* rang  = (const float*)d_in[2];
  const float* nmask = (const float*)d_in[3];
  const float* Wih_t = (const float*)d_in[4];
  const float* Whh_t = (const float*)d_in[5];
  const float* bih_t = (const float*)d_in[6];
  const float* bhh_t = (const float*)d_in[7];
  const float* Wih_n = (const float*)d_in[8];
  const float* Whh_n = (const float*)d_in[9];
  const float* bih_n = (const float*)d_in[10];
  const float* bhh_n = (const float*)d_in[11];
  const float* W1  = (const float*)d_in[12];
  const float* b1  = (const float*)d_in[13];
  const float* W2  = (const float*)d_in[14];
  const float* b2  = (const float*)d_in[15];
  const float* Wf1 = (const float*)d_in[16];
  const float* bf1 = (const float*)d_in[17];
  const float* Wf2 = (const float*)d_in[18];
  const float* bf2 = (const float*)d_in[19];
  const float* Wf3 = (const float*)d_in[20];
  const float* bf3 = (const float*)d_in[21];
  const float* lng = (const float*)d_in[22];
  const float* lnb = (const float*)d_in[23];

  char* ws = (char*)d_ws;
  unsigned short* combined = (unsigned short*)ws;                  // [2048][1152] bf16
  unsigned short* wgt      = (unsigned short*)(ws + 8388608);      // bf16 weights

  hipLaunchKernelGGL(k_prep, dim3(1664), dim3(256), 0, stream,
                     Whh_t, W1, W2, Wf1, Wf2, Wf3, Whh_n, wgt);
  hipLaunchKernelGGL(k_gru_n, dim3(512), dim3(1024), 0, stream,
                     ttraj, ntraj, rang, nmask, Wih_n, bih_n, bhh_n, wgt, b1, b2, combined);
  hipLaunchKernelGGL(k_gru_t, dim3(128), dim3(256), 0, stream,
                     ttraj, Wih_t, bih_t, bhh_t, wgt, combined);
  hipLaunchKernelGGL(k_head, dim3(128), dim3(256), 0, stream,
                     combined, wgt, bf1, bf2, bf3, lng, lnb, (float*)d_out);
}

// Round 12
// 138.231 us; speedup vs baseline: 1.0192x; 1.0192x over previous
//
#include <hip/hip_runtime.h>

typedef __attribute__((ext_vector_type(8))) short short8;
typedef __attribute__((ext_vector_type(4))) float f32x4;

#define SGC (-1.44269504088896341f)   /* -log2(e): sigmoid prescale */
#define THC ( 2.88539008177792681f)   /* 2*log2(e): tanh prescale   */

__device__ __forceinline__ unsigned short f2bf(float f){
  unsigned u = __float_as_uint(f);
  return (unsigned short)((u + 0x7fffu + ((u >> 16) & 1u)) >> 16);
}
__device__ __forceinline__ float bf2f(unsigned short b){
  return __uint_as_float(((unsigned)b) << 16);
}
__device__ __forceinline__ unsigned f2bf_cvt(float f){
  unsigned r;
  asm("v_cvt_pk_bf16_f32 %0, %1, %1" : "=v"(r) : "v"(f));
  return r;
}
__device__ __forceinline__ unsigned f2bf_pk(float lo, float hi){
  unsigned r;
  asm("v_cvt_pk_bf16_f32 %0, %1, %2" : "=v"(r) : "v"(lo), "v"(hi));
  return r;
}

// ---------------- weight conversion: fp32 -> bf16 in ws ----------------
// wgt layout (u16 elems):
//   whhT_b [384*128]  @0        (PRESCALED: rows<256 *SGC, rows>=256 *THC)
//   W1b    [128*96]   @49152    (96 = 68 padded, zeros)
//   W2b    [128*128]  @61440
//   Wf1b   [256*1152] @77824
//   Wf2b   [128*256]  @372736
//   Wf3b   [64*128]   @405504
//   whhN_b [192*64]   @413696   (PRESCALED: rows<128 *SGC, rows>=128 *THC)
//   wxg    [12*16*8]  @425984   (x-proj tiles: j0=W0*s, j1=W1*s, j2=bias*s)
__global__ __launch_bounds__(256) void k_prep(
    const float* __restrict__ Whh_t, const float* __restrict__ W1,
    const float* __restrict__ W2,    const float* __restrict__ Wf1,
    const float* __restrict__ Wf2,   const float* __restrict__ Wf3,
    const float* __restrict__ Whh_n, const float* __restrict__ Wih_n,
    const float* __restrict__ bih_n, const float* __restrict__ bhh_n,
    unsigned short* __restrict__ wgt)
{
  int i = blockIdx.x * 256 + threadIdx.x;
  if (i < 49152){
    int g = i >> 7;
    float s = (g < 256) ? SGC : THC;
    wgt[i] = f2bf(Whh_t[i] * s); return;
  }
  i -= 49152;
  if (i < 12288){ int r = i / 96, c = i % 96;
    wgt[49152 + i] = (c < 68) ? f2bf(W1[r*68 + c]) : (unsigned short)0; return; }
  i -= 12288;
  if (i < 16384){ wgt[61440 + i] = f2bf(W2[i]); return; }
  i -= 16384;
  if (i < 294912){ wgt[77824 + i] = f2bf(Wf1[i]); return; }
  i -= 294912;
  if (i < 32768){ wgt[372736 + i] = f2bf(Wf2[i]); return; }
  i -= 32768;
  if (i < 8192){ wgt[405504 + i] = f2bf(Wf3[i]); return; }
  i -= 8192;
  if (i < 12288){
    int g = i >> 6;
    float s = (g < 128) ? SGC : THC;
    wgt[413696 + i] = f2bf(Whh_n[i] * s); return;
  }
  i -= 12288;
  if (i < 1536){
    int t = i >> 7, rem = i & 127, cc = rem >> 3, j = rem & 7;
    float s = (t < 8) ? SGC : THC;
    int g = (t < 4) ? (t*16 + cc) : (t < 8) ? (64 + (t-4)*16 + cc) : (128 + (t-8)*16 + cc);
    float v = 0.f;
    if (j == 0) v = Wih_n[g*2]   * s;
    if (j == 1) v = Wih_n[g*2+1] * s;
    if (j == 2) v = ((t < 8) ? (bih_n[g] + bhh_n[g]) : bih_n[g]) * s;
    wgt[425984 + i] = f2bf(v); return;
  }
}

// ---------------- neighbor GRU (col-wave) + sector pooling ----------------
// 2048 blocks x 256 threads; ONE batch per block.
// COL-WAVE partition: wave w owns hidden cols [w*16,w*16+16) (tiles w, 4+w,
// 8+w) for ALL 64 seqs. Its 9 B-fragments are step-invariant -> registers,
// loaded once from L2-hot global (no weight LDS staging, no per-step weight
// re-reads: LDS/step/wave drops 38->8 b128; the r5-r11 ~91us was LDS-pipe).
// h in shared [64][72]; 2 barriers/step (read-phase / write-phase).
// LDS 11264 B: hbuf 9216 | xpk/pool 2048. VGPR ~115 under (256,4) cap 128.
__global__ __launch_bounds__(256, 4) void k_gru_n(
    const float* __restrict__ ttraj, const float* __restrict__ ntraj,
    const float* __restrict__ rang,  const float* __restrict__ nmask,
    const float* __restrict__ bhh_n,
    const unsigned short* __restrict__ wgt,
    unsigned short* __restrict__ sf)             // [16384][96] bf16
{
  __shared__ char smem[11264];
  const int tid = threadIdx.x;
  const int w = tid >> 6, u = (tid >> 4) & 3, c = tid & 15;
  const int b = blockIdx.x;
  const unsigned short* whhN_b = wgt + 413696;   // [192][64] prescaled
  const unsigned short* wxg    = wgt + 425984;   // [12][16][8]

  unsigned short* hbuf = (unsigned short*)smem;             // [64][72]
  unsigned* xpk = (unsigned*)(smem + 9216);                 // [8][64] u32
  float* pool   = (float*)(smem + 9216);                    // alias (512 f32)

  // step-invariant B fragments -> registers (direct from L2-hot global)
  short8 Bh[6], Bx[3];
#pragma unroll
  for (int k = 0; k < 3; ++k){           // 0=r, 1=z, 2=n
    int nt = k*4 + w;
    Bh[k*2+0] = *(const short8*)&whhN_b[(nt*16 + c)*64 + u*8];
    Bh[k*2+1] = *(const short8*)&whhN_b[(nt*16 + c)*64 + 32 + u*8];
    Bx[k]     = *(const short8*)&wxg[nt*128 + c*8];
  }
  const float bh_ = bhh_n[128 + w*16 + c] * THC;

  // stage trajectories packed bf16: xpk[step][seq]
  {
    float4 v = ((const float4*)(ntraj + (size_t)b * 1024))[tid];
    int n = tid >> 2, p = (tid & 3) * 2;
    xpk[p*64 + n]     = f2bf_pk(v.x, v.y);
    xpk[(p+1)*64 + n] = f2bf_pk(v.z, v.w);
  }
  __syncthreads();

  float hcur[4][4];                      // [seq-group][q]
#pragma unroll
  for (int sg=0; sg<4; ++sg)
#pragma unroll
    for (int q=0; q<4; ++q) hcur[sg][q] = 0.0f;

  const f32x4 zz = {0.f,0.f,0.f,0.f};

#pragma unroll 1
  for (int st = 0; st < 8; ++st){
    // ---- read phase: A fragments for all 4 seq-groups ----
    short8 a0s[4], a1s[4];
    unsigned xv[4];
#pragma unroll
    for (int sg = 0; sg < 4; ++sg){
      xv[sg] = xpk[st*64 + sg*16 + c];
      if (st > 0){
        a0s[sg] = *(short8*)&hbuf[(sg*16 + c)*72 + u*8];
        a1s[sg] = *(short8*)&hbuf[(sg*16 + c)*72 + 32 + u*8];
      }
    }
    __syncthreads();                     // all reads done before any write

    // ---- compute + write phase ----
#pragma unroll
    for (int sg = 0; sg < 4; ++sg){
      union { unsigned ui[4]; short8 s8; } a2u;
      a2u.ui[0] = (u == 0) ? xv[sg] : 0u;
      a2u.ui[1] = (u == 0) ? 0x3F80u : 0u;   // bf16(1.0) in halfword 2
      a2u.ui[2] = 0u; a2u.ui[3] = 0u;
      short8 a2 = a2u.s8;

      f32x4 aR = __builtin_amdgcn_mfma_f32_16x16x32_bf16(a2, Bx[0], zz, 0,0,0);
      f32x4 aZ = __builtin_amdgcn_mfma_f32_16x16x32_bf16(a2, Bx[1], zz, 0,0,0);
      f32x4 aX = __builtin_amdgcn_mfma_f32_16x16x32_bf16(a2, Bx[2], zz, 0,0,0);
      f32x4 aN = zz;
      if (st > 0){
        aR = __builtin_amdgcn_mfma_f32_16x16x32_bf16(a0s[sg], Bh[0], aR, 0,0,0);
        aR = __builtin_amdgcn_mfma_f32_16x16x32_bf16(a1s[sg], Bh[1], aR, 0,0,0);
        aZ = __builtin_amdgcn_mfma_f32_16x16x32_bf16(a0s[sg], Bh[2], aZ, 0,0,0);
        aZ = __builtin_amdgcn_mfma_f32_16x16x32_bf16(a1s[sg], Bh[3], aZ, 0,0,0);
        aN = __builtin_amdgcn_mfma_f32_16x16x32_bf16(a0s[sg], Bh[4], aN, 0,0,0);
        aN = __builtin_amdgcn_mfma_f32_16x16x32_bf16(a1s[sg], Bh[5], aN, 0,0,0);
      }
#pragma unroll
      for (int q = 0; q < 4; ++q){
        float r = __builtin_amdgcn_rcpf(1.0f + __builtin_amdgcn_exp2f(aR[q]));
        float z = __builtin_amdgcn_rcpf(1.0f + __builtin_amdgcn_exp2f(aZ[q]));
        float hn = aN[q] + bh_;
        float pn = __builtin_fmaf(r, hn, aX[q]);
        float E = __builtin_amdgcn_exp2f(pn);
        float n = __builtin_fmaf(-2.0f, __builtin_amdgcn_rcpf(E + 1.0f), 1.0f);
        float hnew = __builtin_fmaf(z, hcur[sg][q] - n, n);
        hcur[sg][q] = hnew;
        hbuf[(sg*16 + u*4 + q)*72 + w*16 + c] = (unsigned short)f2bf_cvt(hnew);
      }
    }
    __syncthreads();                     // writes visible for next step
  }

  // ---- sector pooling (pool aliases xpk; positions from L2-hot ntraj) ----
  if (tid < 64){
    int n = tid;
    const float* nb = ntraj + (size_t)b*1024 + n*16;
    float px = nb[14], py = nb[15];
    float vx = px - nb[12], vy = py - nb[13];
    float m   = nmask[(size_t)b*64 + n];
    float ang = rang[(size_t)b*64 + n];
    float tx = ttraj[(size_t)b*16 + 14], ty = ttraj[(size_t)b*16 + 15];
    float dx = px - tx, dy = py - ty;
    float dist = __builtin_amdgcn_sqrtf(dx*dx + dy*dy);
    int sid = (int)(ang / 0.78539816339744830962f);
    sid = sid < 0 ? 0 : (sid > 7 ? 7 : sid);
    bool valid = m > 0.0f;
    float wv = valid ? __builtin_amdgcn_exp2f(dist * -0.14426950408889634f) : 0.0f;
    pool[n]       = valid ? dist : 0.0f;
    pool[64 + n]  = valid ? vx   : 0.0f;
    pool[128 + n] = valid ? vy   : 0.0f;
    pool[192 + n] = wv;
    pool[256 + n] = valid ? (float)sid : -1.0f;
  }
  __syncthreads();
  if (tid < 8){
    int s = tid;
    float cnt=0.f, sd=0.f, sx=0.f, sy=0.f, sw=0.f;
#pragma unroll 4
    for (int n=0; n<64; ++n){
      if (pool[256+n] == (float)s){
        cnt += 1.f; sd += pool[n]; sx += pool[64+n]; sy += pool[128+n]; sw += pool[192+n];
      }
    }
    float inv = (cnt > 0.f) ? __builtin_amdgcn_rcpf(cnt) : 0.f;
    pool[320 + s] = cnt;
    pool[328 + s] = sd * inv;
    pool[336 + s] = sx * inv;
    pool[344 + s] = sy * inv;
    pool[352 + s] = __builtin_amdgcn_rcpf(sw + 1e-8f);
  }
  __syncthreads();
#pragma unroll
  for (int rep = 0; rep < 2; ++rep){
    int p = tid + rep*256;
    int s = p >> 6, h = p & 63;
    float fs = (float)s;
    float a = 0.f;
#pragma unroll 4
    for (int n = 0; n < 64; ++n){
      float wmv = (pool[256+n] == fs) ? pool[192+n] : 0.f;
      float nf  = bf2f(hbuf[n*72 + h]);
      a += wmv * nf;
    }
    sf[((size_t)b*8 + s)*96 + 4 + h] = (unsigned short)f2bf_cvt(a * pool[352+s]);
  }
  if (tid < 32){
    int s = tid >> 2, cc = tid & 3;
    sf[((size_t)b*8 + s)*96 + cc] = (unsigned short)f2bf_cvt(pool[320 + cc*8 + s]);
  }
  if (tid < 224){
    int s = tid / 28, cc = 68 + tid % 28;
    sf[((size_t)b*8 + s)*96 + cc] = 0;
  }
}

// ---------------- target GRU: 128 blocks x 256 thr (4 waves) ----------------
__global__ __launch_bounds__(256) void k_gru_t(
    const float* __restrict__ ttraj,
    const float* __restrict__ Wih_t, const float* __restrict__ bih_t, const float* __restrict__ bhh_t,
    const unsigned short* __restrict__ wgt,      // whhT_b [384][128] @0
    unsigned short* __restrict__ combined)       // [2048][1152] bf16
{
  __shared__ char smem[9728];
  const int tid = threadIdx.x, w = tid >> 6, u = (tid >> 4) & 3, c = tid & 15;
  unsigned short* hb0 = (unsigned short*)smem;             // [16][136]
  unsigned short* hb1 = (unsigned short*)(smem + 4352);    // [16][136]
  float* xs = (float*)(smem + 8704);                       // [16][16]

  xs[tid] = ttraj[(size_t)blockIdx.x*256 + tid];

  int ntg[6];
  ntg[0] = 2*w; ntg[1] = 2*w+1;
  ntg[2] = 8+2*w; ntg[3] = 9+2*w;
  ntg[4] = 16+2*w; ntg[5] = 17+2*w;

  short8 Bf[6][4];
#pragma unroll
  for (int lt2 = 0; lt2 < 6; ++lt2){
    const unsigned short* wp = wgt + (ntg[lt2]*16 + c)*128 + u*8;
#pragma unroll
    for (int kk = 0; kk < 4; ++kk)
      Bf[lt2][kk] = *(const short8*)(wp + kk*32);
  }

  float Wr0[2],Wr1[2],BR[2],Wz0[2],Wz1[2],BZ[2],Wn0[2],Wn1[2],BI[2],BH[2];
#pragma unroll
  for (int gt = 0; gt < 2; ++gt){
    int g = w*32 + gt*16 + c;
    Wr0[gt]=Wih_t[g*2]*SGC;        Wr1[gt]=Wih_t[g*2+1]*SGC;        BR[gt]=(bih_t[g]+bhh_t[g])*SGC;
    Wz0[gt]=Wih_t[(128+g)*2]*SGC;  Wz1[gt]=Wih_t[(128+g)*2+1]*SGC;  BZ[gt]=(bih_t[128+g]+bhh_t[128+g])*SGC;
    Wn0[gt]=Wih_t[(256+g)*2]*THC;  Wn1[gt]=Wih_t[(256+g)*2+1]*THC;  BI[gt]=bih_t[256+g]*THC; BH[gt]=bhh_t[256+g]*THC;
  }
  float hcur[2][4];
#pragma unroll
  for (int gt=0; gt<2; ++gt)
#pragma unroll
    for (int q=0; q<4; ++q) hcur[gt][q] = 0.0f;
  __syncthreads();

#pragma unroll 1
  for (int st = 0; st < 8; ++st){
    unsigned short* rbuf = (st & 1) ? hb0 : hb1;
    unsigned short* wbuf = (st & 1) ? hb1 : hb0;
    f32x4 acc[6];
    if (st > 0){
      short8 a0 = *(short8*)&rbuf[c*136 + u*8];
      short8 a1 = *(short8*)&rbuf[c*136 + 32 + u*8];
      short8 a2 = *(short8*)&rbuf[c*136 + 64 + u*8];
      short8 a3 = *(short8*)&rbuf[c*136 + 96 + u*8];
#pragma unroll
      for (int lt2 = 0; lt2 < 6; ++lt2){
        f32x4 t = {0.f,0.f,0.f,0.f};
        t = __builtin_amdgcn_mfma_f32_16x16x32_bf16(a0, Bf[lt2][0], t, 0,0,0);
        t = __builtin_amdgcn_mfma_f32_16x16x32_bf16(a1, Bf[lt2][1], t, 0,0,0);
        t = __builtin_amdgcn_mfma_f32_16x16x32_bf16(a2, Bf[lt2][2], t, 0,0,0);
        acc[lt2] = __builtin_amdgcn_mfma_f32_16x16x32_bf16(a3, Bf[lt2][3], t, 0,0,0);
      }
    } else {
#pragma unroll
      for (int lt2 = 0; lt2 < 6; ++lt2) acc[lt2] = (f32x4){0.f,0.f,0.f,0.f};
    }
#pragma unroll
    for (int gt = 0; gt < 2; ++gt){
#pragma unroll
      for (int q = 0; q < 4; ++q){
        int sq = u*4 + q;
        float x0 = xs[sq*16 + st*2], x1 = xs[sq*16 + st*2 + 1];
        float rp = __builtin_fmaf(Wr0[gt], x0, __builtin_fmaf(Wr1[gt], x1, acc[gt][q] + BR[gt]));
        float zp = __builtin_fmaf(Wz0[gt], x0, __builtin_fmaf(Wz1[gt], x1, acc[2+gt][q] + BZ[gt]));
        float r = __builtin_amdgcn_rcpf(1.0f + __builtin_amdgcn_exp2f(rp));
        float z = __builtin_amdgcn_rcpf(1.0f + __builtin_amdgcn_exp2f(zp));
        float hnv = acc[4+gt][q] + BH[gt];
        float pn = __builtin_fmaf(Wn0[gt], x0, __builtin_fmaf(Wn1[gt], x1, __builtin_fmaf(r, hnv, BI[gt])));
        float E = __builtin_amdgcn_exp2f(pn);
        float n = __builtin_fmaf(-2.0f, __builtin_amdgcn_rcpf(E + 1.0f), 1.0f);
        float hnew = __builtin_fmaf(z, hcur[gt][q] - n, n);
        hcur[gt][q] = hnew;
        if (st < 7){
          wbuf[sq*136 + w*32 + gt*16 + c] = (unsigned short)f2bf_cvt(hnew);
        } else {
          int row = blockIdx.x*16 + sq;
          combined[(size_t)row*1152 + w*32 + gt*16 + c] = (unsigned short)f2bf_cvt(hnew);
        }
      }
    }
    if (st < 7) __syncthreads();
  }
}

// ---------------- MLP1/MLP2 over (b,s) rows: sf -> enc part of combined ----------------
__global__ __launch_bounds__(256) void k_mlp12(
    const unsigned short* __restrict__ sf,    // [16384][96]
    const unsigned short* __restrict__ wgt,
    const float* __restrict__ b1, const float* __restrict__ b2,
    unsigned short* __restrict__ combined)
{
  __shared__ char smem[18432];
  unsigned short* hb = (unsigned short*)smem + (threadIdx.x >> 6) * 2176;  // [16][136]/wave
  float* b1s = (float*)(smem + 17408);
  float* b2s = b1s + 128;
  const unsigned short* w1b = wgt + 49152;
  const unsigned short* w2b = wgt + 61440;
  const int tid = threadIdx.x, w = tid >> 6, u = (tid >> 4) & 3, c = tid & 15;
  if (tid < 128){ b1s[tid] = b1[tid]; b2s[tid] = b2[tid]; }
  __syncthreads();
  const int rowb = blockIdx.x * 64 + w * 16;

  f32x4 acc[8];
#pragma unroll
  for (int nt=0; nt<8; ++nt) acc[nt] = (f32x4){0.f,0.f,0.f,0.f};
#pragma unroll
  for (int kc=0; kc<3; ++kc){
    short8 a = *(const short8*)&sf[(size_t)(rowb + c)*96 + kc*32 + u*8];
#pragma unroll
    for (int nt=0; nt<8; ++nt){
      short8 bb = *(const short8*)&w1b[(nt*16+c)*96 + kc*32 + u*8];
      acc[nt] = __builtin_amdgcn_mfma_f32_16x16x32_bf16(a, bb, acc[nt], 0,0,0);
    }
  }
#pragma unroll
  for (int nt=0; nt<8; ++nt){
    float bias = b1s[nt*16+c];
#pragma unroll
    for (int q=0; q<4; ++q){
      float v = acc[nt][q] + bias; v = v > 0.f ? v : 0.f;
      hb[(u*4+q)*136 + nt*16 + c] = (unsigned short)f2bf_cvt(v);
    }
  }
  f32x4 acc2[8];
#pragma unroll
  for (int nt=0; nt<8; ++nt) acc2[nt] = (f32x4){0.f,0.f,0.f,0.f};
#pragma unroll
  for (int kc=0; kc<4; ++kc){
    short8 a = *(short8*)&hb[c*136 + kc*32 + u*8];
#pragma unroll
    for (int nt=0; nt<8; ++nt){
      short8 bb = *(const short8*)&w2b[(nt*16+c)*128 + kc*32 + u*8];
      acc2[nt] = __builtin_amdgcn_mfma_f32_16x16x32_bf16(a, bb, acc2[nt], 0,0,0);
    }
  }
#pragma unroll
  for (int nt=0; nt<8; ++nt){
    float bias = b2s[nt*16+c];
#pragma unroll
    for (int q=0; q<4; ++q){
      float v = acc2[nt][q] + bias; v = v > 0.f ? v : 0.f;
      int r = rowb + u*4 + q;
      combined[(size_t)(r >> 3)*1152 + 128 + (r & 7)*128 + nt*16 + c] = (unsigned short)f2bf_cvt(v);
    }
  }
}

// ---------------- head: 128 blocks x 256 thr (4 waves) ----------------
__global__ __launch_bounds__(256) void k_head(
    const unsigned short* __restrict__ combined,
    const unsigned short* __restrict__ wgt,
    const float* __restrict__ bf1, const float* __restrict__ bf2, const float* __restrict__ bf3,
    const float* __restrict__ lng, const float* __restrict__ lnb,
    float* __restrict__ out)
{
  __shared__ char smem[15104];
  const int tid = threadIdx.x, w = tid >> 6, u = (tid >> 4) & 3, c = tid & 15;
  unsigned short* f1b = (unsigned short*)smem;                 // [16][264]
  unsigned short* f2b = (unsigned short*)(smem + 8448);        // [16][136]
  float* bf1s = (float*)(smem + 12800); float* bf2s = (float*)(smem + 13824);
  float* bf3s = (float*)(smem + 14336);
  float* lngs = (float*)(smem + 14592); float* lnbs = (float*)(smem + 14848);
  const unsigned short* wf1b = wgt + 77824;
  const unsigned short* wf2b = wgt + 372736;
  const unsigned short* wf3b = wgt + 405504;
  bf1s[tid] = bf1[tid];
  if (tid < 128) bf2s[tid] = bf2[tid];
  if (tid < 64){ bf3s[tid] = bf3[tid]; lngs[tid] = lng[tid]; lnbs[tid] = lnb[tid]; }
  __syncthreads();
  const int rowb = blockIdx.x * 16;

  f32x4 acc[4];
#pragma unroll
  for (int i=0; i<4; ++i) acc[i] = (f32x4){0.f,0.f,0.f,0.f};
#pragma unroll 4
  for (int kc=0; kc<36; ++kc){
    short8 a = *(const short8*)&combined[(size_t)(rowb + c)*1152 + kc*32 + u*8];
#pragma unroll
    for (int i=0; i<4; ++i){
      int nt = w*4 + i;
      short8 bb = *(const short8*)&wf1b[(size_t)(nt*16+c)*1152 + kc*32 + u*8];
      acc[i] = __builtin_amdgcn_mfma_f32_16x16x32_bf16(a, bb, acc[i], 0,0,0);
    }
  }
#pragma unroll
  for (int i=0; i<4; ++i){
    int nt = w*4 + i;
    float bias = bf1s[nt*16+c];
#pragma unroll
    for (int q=0; q<4; ++q){
      float v = acc[i][q] + bias; v = v > 0.f ? v : 0.f;
      f1b[(u*4+q)*264 + nt*16 + c] = (unsigned short)f2bf_cvt(v);
    }
  }
  __syncthreads();

  f32x4 acc2[2];
#pragma unroll
  for (int i=0; i<2; ++i) acc2[i] = (f32x4){0.f,0.f,0.f,0.f};
#pragma unroll
  for (int kc=0; kc<8; ++kc){
    short8 a = *(short8*)&f1b[c*264 + kc*32 + u*8];
#pragma unroll
    for (int i=0; i<2; ++i){
      int nt = w*2 + i;
      short8 bb = *(const short8*)&wf2b[(nt*16+c)*256 + kc*32 + u*8];
      acc2[i] = __builtin_amdgcn_mfma_f32_16x16x32_bf16(a, bb, acc2[i], 0,0,0);
    }
  }
#pragma unroll
  for (int i=0; i<2; ++i){
    int nt = w*2 + i;
    float bias = bf2s[nt*16+c];
#pragma unroll
    for (int q=0; q<4; ++q){
      float v = acc2[i][q] + bias; v = v > 0.f ? v : 0.f;
      f2b[(u*4+q)*136 + nt*16 + c] = (unsigned short)f2bf_cvt(v);
    }
  }
  __syncthreads();

  f32x4 acc3[4];
#pragma unroll
  for (int nt=0; nt<4; ++nt) acc3[nt] = (f32x4){0.f,0.f,0.f,0.f};
#pragma unroll
  for (int kc=0; kc<4; ++kc){
    short8 a = *(short8*)&f2b[c*136 + kc*32 + u*8];
#pragma unroll
    for (int nt=0; nt<4; ++nt){
      short8 bb = *(const short8*)&wf3b[(nt*16+c)*128 + kc*32 + u*8];
      acc3[nt] = __builtin_amdgcn_mfma_f32_16x16x32_bf16(a, bb, acc3[nt], 0,0,0);
    }
  }
  if (w == 0){
    float v[4][4];
#pragma unroll
    for (int nt=0; nt<4; ++nt){
      float bias = bf3s[nt*16+c];
#pragma unroll
      for (int q=0; q<4; ++q){
        float t = acc3[nt][q] + bias; v[nt][q] = t > 0.f ? t : 0.f;
      }
    }
#pragma unroll
    for (int q=0; q<4; ++q){
      float p = v[0][q] + v[1][q] + v[2][q] + v[3][q];
      p += __shfl_xor(p, 1); p += __shfl_xor(p, 2); p += __shfl_xor(p, 4); p += __shfl_xor(p, 8);
      float mu = p * 0.015625f;
      float d0 = v[0][q]-mu, d1 = v[1][q]-mu, d2 = v[2][q]-mu, d3 = v[3][q]-mu;
      float p2 = d0*d0 + d1*d1 + d2*d2 + d3*d3;
      p2 += __shfl_xor(p2, 1); p2 += __shfl_xor(p2, 2); p2 += __shfl_xor(p2, 4); p2 += __shfl_xor(p2, 8);
      float rstd = __builtin_amdgcn_rsqf(p2 * 0.015625f + 1e-5f);
      int row = rowb + u*4 + q;
#pragma unroll
      for (int nt=0; nt<4; ++nt){
        int col = nt*16 + c;
        out[(size_t)row*64 + col] = (v[nt][q] - mu) * rstd * lngs[col] + lnbs[col];
      }
    }
  }
}

extern "C" void kernel_launch(void* const* d_in, const int* in_sizes, int n_in,
                              void* d_out, int out_size, void* d_ws, size_t ws_size,
                              hipStream_t stream)
{
  const float* ttraj = (const float*)d_in[0];
  const float* ntraj = (const float*)d_in[1];
  const float* rang  = (const float*)d_in[2];
  const float* nmask = (const float*)d_in[3];
  const float* Wih_t = (const float*)d_in[4];
  const float* Whh_t = (const float*)d_in[5];
  const float* bih_t = (const float*)d_in[6];
  const float* bhh_t = (const float*)d_in[7];
  const float* Wih_n = (const float*)d_in[8];
  const float* Whh_n = (const float*)d_in[9];
  const float* bih_n = (const float*)d_in[10];
  const float* bhh_n = (const float*)d_in[11];
  const float* W1  = (const float*)d_in[12];
  const float* b1  = (const float*)d_in[13];
  const float* W2  = (const float*)d_in[14];
  const float* b2  = (const float*)d_in[15];
  const float* Wf1 = (const float*)d_in[16];
  const float* bf1 = (const float*)d_in[17];
  const float* Wf2 = (const float*)d_in[18];
  const float* bf2 = (const float*)d_in[19];
  const float* Wf3 = (const float*)d_in[20];
  const float* bf3 = (const float*)d_in[21];
  const float* lng = (const float*)d_in[22];
  const float* lnb = (const float*)d_in[23];

  char* ws = (char*)d_ws;
  unsigned short* combined = (unsigned short*)ws;                  // [2048][1152] bf16
  unsigned short* sf       = (unsigned short*)(ws + 5242880);      // [16384][96] bf16
  unsigned short* wgt      = (unsigned short*)(ws + 8388608);      // bf16 weights

  hipLaunchKernelGGL(k_prep, dim3(1670), dim3(256), 0, stream,
                     Whh_t, W1, W2, Wf1, Wf2, Wf3, Whh_n, Wih_n, bih_n, bhh_n, wgt);
  hipLaunchKernelGGL(k_gru_n, dim3(2048), dim3(256), 0, stream,
                     ttraj, ntraj, rang, nmask, bhh_n, wgt, sf);
  hipLaunchKernelGGL(k_gru_t, dim3(128), dim3(256), 0, stream,
                     ttraj, Wih_t, bih_t, bhh_t, wgt, combined);
  hipLaunchKernelGGL(k_mlp12, dim3(256), dim3(256), 0, stream, sf, wgt, b1, b2, combined);
  hipLaunchKernelGGL(k_head, dim3(128), dim3(256), 0, stream,
                     combined, wgt, bf1, bf2, bf3, lng, lnb, (float*)d_out);
}